// Round 2
// baseline (1337.865 us; speedup 1.0000x reference)
//
#include <hip/hip_runtime.h>
#include <hip/hip_fp16.h>
#include <math.h>

#define NSLOPE 0.2f
#define BSH 6          // 64 nodes per bucket
#define BK  64
#define UMASK ((1 << 18) - 1)   // node id fits 18 bits (N <= 262144)

__device__ __forceinline__ float lrelu(float v) { return v > 0.f ? v : NSLOPE * v; }

// ---------------------------------------------------------------- flag detect
// int64 edge_index -> every u64 word < 2^32; int32 -> combined words huge.
__global__ void k_flag(const unsigned long long* __restrict__ p, int* __restrict__ flag) {
    if (blockIdx.x == 0 && threadIdx.x == 0) {
        int ok = 1;
        for (int i = 0; i < 256; i++)
            if (p[i] >= (1ull << 32)) { ok = 0; break; }
        *flag = ok;  // 1 = int64 layout, 0 = int32 layout
    }
}

__device__ __forceinline__ void load_edge(const void* ei, long long E, long long i, int fl,
                                          int& u, int& v) {
    if (fl) {
        const long long* p = (const long long*)ei;
        u = (int)p[i]; v = (int)p[E + i];
    } else {
        const int* p = (const int*)ei;
        u = p[i]; v = p[E + i];
    }
}

// ---------------------------------------------------------------- node prep
// h1 = x @ W1 (3->16) both directions (fp16 storage), fp32 attention scores,
// zero degree + bucket-cursor arrays.
__global__ void k_prep(const float* __restrict__ x,
                       const float* __restrict__ W1, const float* __restrict__ as1, const float* __restrict__ ad1,
                       const float* __restrict__ W1r, const float* __restrict__ as1r, const float* __restrict__ ad1r,
                       __half* __restrict__ h1f, __half* __restrict__ h1r,
                       float* __restrict__ s1sf, float* __restrict__ s1df,
                       float* __restrict__ s1sr, float* __restrict__ s1dr,
                       int* __restrict__ degf, int* __restrict__ degr,
                       int* __restrict__ bcurf, int* __restrict__ bcurr, int nbuck16, int N) {
    int i = blockIdx.x * blockDim.x + threadIdx.x;
    if (i < nbuck16) { bcurf[i] = 0; bcurr[i] = 0; }
    if (i >= N) return;
    degf[i] = 0; degr[i] = 0;
    float x0 = x[3 * i], x1 = x[3 * i + 1], x2 = x[3 * i + 2];
    float ssf = 0.f, sdf = 0.f, ssr = 0.f, sdr = 0.f;
    union H8 { float4 f4[2]; __half2 h2[8]; } hf, hr;
#pragma unroll
    for (int k = 0; k < 16; k += 2) {
        float a0 = x0 * W1[k]     + x1 * W1[16 + k]     + x2 * W1[32 + k];
        float a1 = x0 * W1[k + 1] + x1 * W1[17 + k]     + x2 * W1[33 + k];
        ssf += a0 * as1[k] + a1 * as1[k + 1];
        sdf += a0 * ad1[k] + a1 * ad1[k + 1];
        hf.h2[k >> 1] = __floats2half2_rn(a0, a1);
        float c0 = x0 * W1r[k]     + x1 * W1r[16 + k]   + x2 * W1r[32 + k];
        float c1 = x0 * W1r[k + 1] + x1 * W1r[17 + k]   + x2 * W1r[33 + k];
        ssr += c0 * as1r[k] + c1 * as1r[k + 1];
        sdr += c0 * ad1r[k] + c1 * ad1r[k + 1];
        hr.h2[k >> 1] = __floats2half2_rn(c0, c1);
    }
    float4* pf = (float4*)(h1f + 16 * i);
    pf[0] = hf.f4[0]; pf[1] = hf.f4[1];
    float4* pr = (float4*)(h1r + 16 * i);
    pr[0] = hr.f4[0]; pr[1] = hr.f4[1];
    s1sf[i] = ssf; s1df[i] = sdf; s1sr[i] = ssr; s1dr[i] = sdr;
}

// ---------------------------------------------------------------- degree hist
__global__ void k_hist(const void* __restrict__ ei, long long E, const int* __restrict__ flag,
                       int* __restrict__ degf, int* __restrict__ degr) {
    long long i = blockIdx.x * (long long)blockDim.x + threadIdx.x;
    if (i >= E) return;
    int u, v;
    load_edge(ei, E, i, *flag, u, v);
    atomicAdd(&degf[v], 1);  // fwd: dst = e1
    atomicAdd(&degr[u], 1);  // rev: dst = e0
}

// ---------------------------------------------------------------- excl. scan
// Single block of 1024 threads; also writes off[N] = total.
__global__ void k_scan(const int* __restrict__ degf, int* __restrict__ offf,
                       const int* __restrict__ degr, int* __restrict__ offr, int N) {
    __shared__ int sm[1024];
    int t = threadIdx.x;
    int chunk = (N + 1023) >> 10;
    for (int a = 0; a < 2; a++) {
        const int* deg = a ? degr : degf;
        int* off = a ? offr : offf;
        int begin = t * chunk; if (begin > N) begin = N;
        int end = begin + chunk; if (end > N) end = N;
        int s = 0;
        for (int i = begin; i < end; i++) s += deg[i];
        __syncthreads();
        sm[t] = s;
        __syncthreads();
        for (int od = 1; od < 1024; od <<= 1) {
            int tmp = (t >= od) ? sm[t - od] : 0;
            __syncthreads();
            sm[t] += tmp;
            __syncthreads();
        }
        if (t == 1023) off[N] = sm[1023];
        int base = sm[t] - s;  // exclusive prefix
        for (int i = begin; i < end; i++) { off[i] = base; base += deg[i]; }
        __syncthreads();
    }
}

// ---------------------------------------------------------------- bucket bin
// Scatter packed edge records to per-bucket frontiers (line-coalesced in L2).
// Record: neighbor_id | (local_dst << 18).
__global__ void k_bin(const void* __restrict__ ei, long long E, const int* __restrict__ flag,
                      const int* __restrict__ offf, int* __restrict__ bcurf, unsigned* __restrict__ binf,
                      const int* __restrict__ offr, int* __restrict__ bcurr, unsigned* __restrict__ binr) {
    long long i = blockIdx.x * (long long)blockDim.x + threadIdx.x;
    if (i >= E) return;
    int u, v;
    load_edge(ei, E, i, *flag, u, v);
    {
        int b = v >> BSH;
        int base = offf[b << BSH];
        int p = atomicAdd(&bcurf[b * 16], 1);
        binf[base + p] = (unsigned)u | ((unsigned)(v & (BK - 1)) << 18);
    }
    {
        int b = u >> BSH;
        int base = offr[b << BSH];
        int p = atomicAdd(&bcurr[b * 16], 1);
        binr[base + p] = (unsigned)v | ((unsigned)(u & (BK - 1)) << 18);
    }
}

// ---------------------------------------------------------------- CSR fill
// One block per bucket; writes confined to the bucket's ~8KB CSR window.
__global__ void k_fillb(const unsigned* __restrict__ binf, const int* __restrict__ offf, int* __restrict__ csrf,
                        const unsigned* __restrict__ binr, const int* __restrict__ offr, int* __restrict__ csrr,
                        int nbuck, int N) {
    int b = blockIdx.x;
    int dir = (b >= nbuck);
    int bb = dir ? b - nbuck : b;
    const unsigned* bin = dir ? binr : binf;
    const int* off = dir ? offr : offf;
    int* csr = dir ? csrr : csrf;
    int v0 = bb << BSH;
    int nv = min(BK, N - v0);
    __shared__ int loff[BK + 1];
    __shared__ int cnt[BK];
    int t = threadIdx.x;
    if (t <= nv) loff[t] = off[v0 + t];
    if (t < BK) cnt[t] = 0;
    __syncthreads();
    int start = loff[0], end = loff[nv];
    for (int i = start + t; i < end; i += blockDim.x) {
        unsigned w = __builtin_nontemporal_load(bin + i);
        int u = (int)(w & UMASK);
        int lv = (int)(w >> 18);
        int pos = atomicAdd(&cnt[lv], 1);
        csr[loff[lv] + pos] = u;
    }
}

// ---------------------------------------------------------------- conv1 agg (one direction)
// Online softmax over in-edges + implicit self loop; fused relu + W2 proj.
__global__ void k_agg1(const __half* __restrict__ h1, const float* __restrict__ s1s, const float* __restrict__ s1d,
                       const int* __restrict__ off, const int* __restrict__ csr,
                       const float* __restrict__ b1, const float* __restrict__ W2,
                       const float* __restrict__ as2, const float* __restrict__ ad2,
                       float2* __restrict__ p2, float* __restrict__ s2d, int N) {
    int v = blockIdx.x * blockDim.x + threadIdx.x;
    if (v >= N) return;
    float sd = s1d[v];
    int st = off[v];
    int n = off[v + 1] - st;
    // self loop first: m = e_self, d = 1, acc = h1[v]
    float m = lrelu(s1s[v] + sd);
    float d = 1.f;
    float acc[16];
    union H8 { float4 f4[2]; __half2 h2[8]; } hh;
    {
        const float4* hp = (const float4*)(h1 + 16 * v);
        hh.f4[0] = hp[0]; hh.f4[1] = hp[1];
#pragma unroll
        for (int r = 0; r < 8; r++) {
            float2 f = __half22float2(hh.h2[r]);
            acc[2 * r] = f.x; acc[2 * r + 1] = f.y;
        }
    }
    int nxt = (n > 0) ? __builtin_nontemporal_load(csr + st) : 0;
    for (int j = 0; j < n; j++) {
        int u = nxt;
        if (j + 1 < n) nxt = __builtin_nontemporal_load(csr + st + j + 1);
        float e = lrelu(s1s[u] + sd);
        float mn = fmaxf(m, e);
        float sc = __expf(m - mn);
        float du = __expf(e - mn);
        d = d * sc + du;
        const float4* hp = (const float4*)(h1 + 16 * u);
        hh.f4[0] = hp[0]; hh.f4[1] = hp[1];
#pragma unroll
        for (int r = 0; r < 8; r++) {
            float2 f = __half22float2(hh.h2[r]);
            acc[2 * r]     = acc[2 * r]     * sc + du * f.x;
            acc[2 * r + 1] = acc[2 * r + 1] * sc + du * f.y;
        }
        m = mn;
    }
    float inv = 1.f / (d + 1e-16f);
    float h2v = 0.f;
#pragma unroll
    for (int k = 0; k < 16; k++) {
        float o = fmaxf(acc[k] * inv + b1[k], 0.f);
        h2v += o * W2[k];
    }
    p2[v] = make_float2(h2v, h2v * as2[0]);
    s2d[v] = h2v * ad2[0];
}

// ---------------------------------------------------------------- conv2 agg + combine
__global__ void k_agg2(const float2* __restrict__ p2f, const float* __restrict__ s2df,
                       const int* __restrict__ offf, const int* __restrict__ csrf,
                       const float2* __restrict__ p2r, const float* __restrict__ s2dr,
                       const int* __restrict__ offr, const int* __restrict__ csrr,
                       const float* __restrict__ b2, const float* __restrict__ b2r,
                       float* __restrict__ out, int N) {
    int v = blockIdx.x * blockDim.x + threadIdx.x;
    if (v >= N) return;
    float of;
    {
        float sd = s2df[v];
        int st = offf[v], n = offf[v + 1] - st;
        float2 ts = p2f[v];
        float m = lrelu(ts.y + sd);
        float d = 1.f, a = ts.x;
        int nxt = (n > 0) ? __builtin_nontemporal_load(csrf + st) : 0;
        for (int j = 0; j < n; j++) {
            int u = nxt;
            if (j + 1 < n) nxt = __builtin_nontemporal_load(csrf + st + j + 1);
            float2 t = p2f[u];
            float e = lrelu(t.y + sd);
            float mn = fmaxf(m, e);
            float sc = __expf(m - mn);
            float du = __expf(e - mn);
            d = d * sc + du;
            a = a * sc + du * t.x;
            m = mn;
        }
        of = a / (d + 1e-16f) + b2[0];
    }
    float orv;
    {
        float sd = s2dr[v];
        int st = offr[v], n = offr[v + 1] - st;
        float2 ts = p2r[v];
        float m = lrelu(ts.y + sd);
        float d = 1.f, a = ts.x;
        int nxt = (n > 0) ? __builtin_nontemporal_load(csrr + st) : 0;
        for (int j = 0; j < n; j++) {
            int u = nxt;
            if (j + 1 < n) nxt = __builtin_nontemporal_load(csrr + st + j + 1);
            float2 t = p2r[u];
            float e = lrelu(t.y + sd);
            float mn = fmaxf(m, e);
            float sc = __expf(m - mn);
            float du = __expf(e - mn);
            d = d * sc + du;
            a = a * sc + du * t.x;
            m = mn;
        }
        orv = a / (d + 1e-16f) + b2r[0];
    }
    out[v] = 0.5f * (of + orv);
}

// ================================================================ launch
extern "C" void kernel_launch(void* const* d_in, const int* in_sizes, int n_in,
                              void* d_out, int out_size, void* d_ws, size_t ws_size,
                              hipStream_t stream) {
    const float* x   = (const float*)d_in[0];
    const void*  ei  = d_in[1];
    const float* W1  = (const float*)d_in[2];
    const float* as1 = (const float*)d_in[3];
    const float* ad1 = (const float*)d_in[4];
    const float* b1  = (const float*)d_in[5];
    const float* W2  = (const float*)d_in[6];
    const float* as2 = (const float*)d_in[7];
    const float* ad2 = (const float*)d_in[8];
    const float* b2  = (const float*)d_in[9];
    const float* W1r  = (const float*)d_in[10];
    const float* as1r = (const float*)d_in[11];
    const float* ad1r = (const float*)d_in[12];
    const float* b1r  = (const float*)d_in[13];
    const float* W2r  = (const float*)d_in[14];
    const float* as2r = (const float*)d_in[15];
    const float* ad2r = (const float*)d_in[16];
    const float* b2r  = (const float*)d_in[17];

    const int N = in_sizes[0] / 3;
    const long long E = in_sizes[1] / 2;
    const int NBUCK = (N + BK - 1) >> BSH;

    char* w = (char*)d_ws;
    size_t o = 0;
    auto A = [&](size_t bytes) { o = (o + 255) & ~(size_t)255; size_t r = o; o += bytes; return r; };
    size_t oFlag = A(64);
    size_t oH1f  = A(sizeof(__half) * 16 * N);
    size_t oH1r  = A(sizeof(__half) * 16 * N);
    size_t oS1sf = A(sizeof(float) * N);
    size_t oS1df = A(sizeof(float) * N);
    size_t oS1sr = A(sizeof(float) * N);
    size_t oS1dr = A(sizeof(float) * N);
    size_t oP2f  = A(sizeof(float2) * N);
    size_t oS2df = A(sizeof(float) * N);
    size_t oP2r  = A(sizeof(float2) * N);
    size_t oS2dr = A(sizeof(float) * N);
    size_t oDegf = A(sizeof(int) * N);
    size_t oDegr = A(sizeof(int) * N);
    size_t oOfff = A(sizeof(int) * (N + 1));
    size_t oOffr = A(sizeof(int) * (N + 1));
    size_t oBcf  = A(sizeof(int) * NBUCK * 16);
    size_t oBcr  = A(sizeof(int) * NBUCK * 16);
    size_t oBinf = A(sizeof(unsigned) * E);
    size_t oBinr = A(sizeof(unsigned) * E);
    size_t oCsrf = A(sizeof(int) * E);
    size_t oCsrr = A(sizeof(int) * E);
    (void)ws_size; (void)n_in; (void)out_size;

    int*      flag = (int*)(w + oFlag);
    __half*   h1f  = (__half*)(w + oH1f);
    __half*   h1r  = (__half*)(w + oH1r);
    float*    s1sf = (float*)(w + oS1sf);
    float*    s1df = (float*)(w + oS1df);
    float*    s1sr = (float*)(w + oS1sr);
    float*    s1dr = (float*)(w + oS1dr);
    float2*   p2f  = (float2*)(w + oP2f);
    float*    s2df = (float*)(w + oS2df);
    float2*   p2r  = (float2*)(w + oP2r);
    float*    s2dr = (float*)(w + oS2dr);
    int* degf = (int*)(w + oDegf);
    int* degr = (int*)(w + oDegr);
    int* offf = (int*)(w + oOfff);
    int* offr = (int*)(w + oOffr);
    int* bcurf = (int*)(w + oBcf);
    int* bcurr = (int*)(w + oBcr);
    unsigned* binf = (unsigned*)(w + oBinf);
    unsigned* binr = (unsigned*)(w + oBinr);
    int* csrf = (int*)(w + oCsrf);
    int* csrr = (int*)(w + oCsrr);

    dim3 blk(256);
    dim3 gN((N + 255) / 256);
    dim3 gE((unsigned)((E + 255) / 256));

    k_flag<<<1, 64, 0, stream>>>((const unsigned long long*)ei, flag);
    k_prep<<<gN, blk, 0, stream>>>(x, W1, as1, ad1, W1r, as1r, ad1r,
                                   h1f, h1r, s1sf, s1df, s1sr, s1dr,
                                   degf, degr, bcurf, bcurr, NBUCK * 16, N);
    k_hist<<<gE, blk, 0, stream>>>(ei, E, flag, degf, degr);
    k_scan<<<1, 1024, 0, stream>>>(degf, offf, degr, offr, N);
    k_bin<<<gE, blk, 0, stream>>>(ei, E, flag, offf, bcurf, binf, offr, bcurr, binr);
    k_fillb<<<dim3(2 * NBUCK), blk, 0, stream>>>(binf, offf, csrf, binr, offr, csrr, NBUCK, N);
    k_agg1<<<gN, blk, 0, stream>>>(h1f, s1sf, s1df, offf, csrf, b1, W2, as2, ad2, p2f, s2df, N);
    k_agg1<<<gN, blk, 0, stream>>>(h1r, s1sr, s1dr, offr, csrr, b1r, W2r, as2r, ad2r, p2r, s2dr, N);
    k_agg2<<<gN, blk, 0, stream>>>(p2f, s2df, offf, csrf, p2r, s2dr, offr, csrr,
                                   b2, b2r, (float*)d_out, N);
}

// Round 3
// 380.350 us; speedup vs baseline: 3.5175x; 3.5175x over previous
//
#include <hip/hip_runtime.h>
#include <hip/hip_fp16.h>
#include <math.h>

#define NSLOPE 0.2f
#define BSH 8                  // 256 nodes per bucket
#define BNODES 256
#define GPART 256              // partition blocks for hist/scatter
#define NEG_SENT -1e30f
#define NID_MASK 0x1FFFF       // node id fits 17 bits (N <= 131072)
#define MAXNB 1024             // max buckets (N <= 262144)

__device__ __forceinline__ float lrelu(float v) { return v > 0.f ? v : NSLOPE * v; }

// ---------------------------------------------------------------- flag detect
// int64 edge_index -> every u64 word < 2^32; int32 -> combined words huge.
__global__ void k_flag(const unsigned long long* __restrict__ p, int* __restrict__ flag) {
    if (blockIdx.x == 0 && threadIdx.x == 0) {
        int ok = 1;
        for (int i = 0; i < 256; i++)
            if (p[i] >= (1ull << 32)) { ok = 0; break; }
        *flag = ok;  // 1 = int64 layout, 0 = int32 layout
    }
}

__device__ __forceinline__ void load_edge(const void* ei, long long E, long long i, int fl,
                                          int& u, int& v) {
    if (fl) {
        const long long* p = (const long long*)ei;
        u = (int)p[i]; v = (int)p[E + i];
    } else {
        const int* p = (const int*)ei;
        u = p[i]; v = p[E + i];
    }
}

// ---------------------------------------------------------------- node prep
// h1 = x @ W1 (3->16) both directions (fp16 storage), fp32 attention scores.
__global__ void k_prep(const float* __restrict__ x,
                       const float* __restrict__ W1, const float* __restrict__ as1, const float* __restrict__ ad1,
                       const float* __restrict__ W1r, const float* __restrict__ as1r, const float* __restrict__ ad1r,
                       __half* __restrict__ h1f, __half* __restrict__ h1r,
                       float* __restrict__ s1sf, float* __restrict__ s1df,
                       float* __restrict__ s1sr, float* __restrict__ s1dr, int N) {
    int i = blockIdx.x * blockDim.x + threadIdx.x;
    if (i >= N) return;
    float x0 = x[3 * i], x1 = x[3 * i + 1], x2 = x[3 * i + 2];
    float ssf = 0.f, sdf = 0.f, ssr = 0.f, sdr = 0.f;
    union H8 { float4 f4[2]; __half2 h2[8]; } hf, hr;
#pragma unroll
    for (int k = 0; k < 16; k += 2) {
        float a0 = x0 * W1[k]     + x1 * W1[16 + k] + x2 * W1[32 + k];
        float a1 = x0 * W1[k + 1] + x1 * W1[17 + k] + x2 * W1[33 + k];
        ssf += a0 * as1[k] + a1 * as1[k + 1];
        sdf += a0 * ad1[k] + a1 * ad1[k + 1];
        hf.h2[k >> 1] = __floats2half2_rn(a0, a1);
        float c0 = x0 * W1r[k]     + x1 * W1r[16 + k] + x2 * W1r[32 + k];
        float c1 = x0 * W1r[k + 1] + x1 * W1r[17 + k] + x2 * W1r[33 + k];
        ssr += c0 * as1r[k] + c1 * as1r[k + 1];
        sdr += c0 * ad1r[k] + c1 * ad1r[k + 1];
        hr.h2[k >> 1] = __floats2half2_rn(c0, c1);
    }
    float4* pf = (float4*)(h1f + 16 * i);
    pf[0] = hf.f4[0]; pf[1] = hf.f4[1];
    float4* pr = (float4*)(h1r + 16 * i);
    pr[0] = hr.f4[0]; pr[1] = hr.f4[1];
    s1sf[i] = ssf; s1df[i] = sdf; s1sr[i] = ssr; s1dr[i] = sdr;
}

// ---------------------------------------------------------------- per-block bucket hist
// counts[dir][g][b], written once per slot (no zeroing of ws needed).
__global__ void k_hist5(const void* __restrict__ ei, long long E, const int* __restrict__ flag,
                        int* __restrict__ counts, int NB) {
    __shared__ int h[2 * MAXNB];
    int t = threadIdx.x;
    for (int c = t; c < 2 * NB; c += blockDim.x) h[c] = 0;
    __syncthreads();
    int fl = *flag;
    long long chunk = (E + GPART - 1) / GPART;
    long long start = (long long)blockIdx.x * chunk;
    long long end = start + chunk; if (end > E) end = E;
    for (long long i = start + t; i < end; i += blockDim.x) {
        int u, v;
        load_edge(ei, E, i, fl, u, v);
        atomicAdd(&h[v >> BSH], 1);            // fwd: dst = e1
        atomicAdd(&h[NB + (u >> BSH)], 1);     // rev: dst = e0
    }
    __syncthreads();
    for (int c = t; c < 2 * NB; c += blockDim.x) {
        int dir = c >= NB;
        int bb = dir ? c - NB : c;
        counts[(long long)dir * GPART * NB + (long long)blockIdx.x * NB + bb] = h[c];
    }
}

// ---------------------------------------------------------------- scan
// In-place: counts -> per-(block,bucket) exclusive write bases (within dir).
// Also writes bucketbase[dir][b] (NB+1 entries per dir).
__global__ void k_scan6(int* __restrict__ counts, int* __restrict__ bucketbase, int NB) {
    __shared__ int sm[1024];
    int t = threadIdx.x;
    int ncol = 2 * NB;
    // phase 1: column totals (coalesced: per g-step, consecutive t -> consecutive addr)
    int total = 0;
    int dir = 0, bb = 0;
    if (t < ncol) {
        dir = t / NB; bb = t - dir * NB;
        const int* p = counts + (long long)dir * GPART * NB + bb;
        for (int g = 0; g < GPART; g++) total += p[(long long)g * NB];
    }
    sm[t] = (t < ncol) ? total : 0;
    __syncthreads();
    for (int od = 1; od < 1024; od <<= 1) {
        int tmp = (t >= od) ? sm[t - od] : 0;
        __syncthreads();
        sm[t] += tmp;
        __syncthreads();
    }
    int tot0 = sm[NB - 1];                    // total of dir 0
    int excl = sm[t] - ((t < ncol) ? total : 0);
    if (t < ncol) {
        int base = excl - (dir ? tot0 : 0);   // exclusive within direction
        bucketbase[dir * (NB + 1) + bb] = base;
        if (bb == NB - 1) bucketbase[dir * (NB + 1) + NB] = base + total;
        // phase 2: rewrite column -> per-block bases
        int* p = counts + (long long)dir * GPART * NB + bb;
        int cur = base;
        for (int g = 0; g < GPART; g++) {
            int c = p[(long long)g * NB];
            p[(long long)g * NB] = cur;
            cur += c;
        }
    }
}

// ---------------------------------------------------------------- scatter to bins
// Each block's writes per bucket form a private contiguous run (~128B).
__global__ void k_scatter7(const void* __restrict__ ei, long long E, const int* __restrict__ flag,
                           const int* __restrict__ counts, int NB,
                           unsigned* __restrict__ binf, unsigned* __restrict__ binr) {
    __shared__ int cur[2 * MAXNB];
    int t = threadIdx.x;
    for (int c = t; c < 2 * NB; c += blockDim.x) {
        int dir = c >= NB;
        int bb = dir ? c - NB : c;
        cur[c] = counts[(long long)dir * GPART * NB + (long long)blockIdx.x * NB + bb];
    }
    __syncthreads();
    int fl = *flag;
    long long chunk = (E + GPART - 1) / GPART;
    long long start = (long long)blockIdx.x * chunk;
    long long end = start + chunk; if (end > E) end = E;
    for (long long i = start + t; i < end; i += blockDim.x) {
        int u, v;
        load_edge(ei, E, i, fl, u, v);
        {
            int p = atomicAdd(&cur[v >> BSH], 1);
            binf[p] = (unsigned)u | ((unsigned)(v & (BNODES - 1)) << 17);
        }
        {
            int p = atomicAdd(&cur[NB + (u >> BSH)], 1);
            binr[p] = (unsigned)v | ((unsigned)(u & (BNODES - 1)) << 17);
        }
    }
}

// ---------------------------------------------------------------- bucket fill
// One block per (dir,bucket): local node degrees + scan -> off[] slice, then
// scatter CSR inside the bucket's window (L2-coalesced writes).
__global__ void k_fill8(const unsigned* __restrict__ binf, const unsigned* __restrict__ binr,
                        const int* __restrict__ bucketbase,
                        int* __restrict__ offf, int* __restrict__ offr,
                        int* __restrict__ csrf, int* __restrict__ csrr, int NB, int N) {
    int b = blockIdx.x;
    int dir = (b >= NB);
    int bb = dir ? b - NB : b;
    const unsigned* bin = dir ? binr : binf;
    int* off = dir ? offr : offf;
    int* csr = dir ? csrr : csrf;
    int bstart = bucketbase[dir * (NB + 1) + bb];
    int bend   = bucketbase[dir * (NB + 1) + bb + 1];
    int v0 = bb << BSH;
    int nv = N - v0; if (nv > BNODES) nv = BNODES;
    __shared__ int cnt[BNODES];
    __shared__ int sc[BNODES];
    int t = threadIdx.x;
    if (t < BNODES) cnt[t] = 0;
    __syncthreads();
    for (int i = bstart + t; i < bend; i += blockDim.x)
        atomicAdd(&cnt[bin[i] >> 17], 1);
    __syncthreads();
    int myc = (t < BNODES) ? cnt[t] : 0;
    if (t < BNODES) sc[t] = myc;
    __syncthreads();
    for (int od = 1; od < BNODES; od <<= 1) {
        int tmp = (t < BNODES && t >= od) ? sc[t - od] : 0;
        __syncthreads();
        if (t < BNODES) sc[t] += tmp;
        __syncthreads();
    }
    if (t < BNODES) {
        int ci = bstart + sc[t] - myc;   // absolute exclusive position
        if (t < nv) off[v0 + t] = ci;
        cnt[t] = ci;                      // becomes the scatter cursor
    }
    if (t == 0 && v0 + nv == N) off[N] = bend;
    __syncthreads();
    for (int i = bstart + t; i < bend; i += blockDim.x) {
        unsigned rec = bin[i];
        int lv = (int)(rec >> 17);
        int p = atomicAdd(&cnt[lv], 1);
        csr[p] = (int)(rec & NID_MASK);
    }
}

// ---------------------------------------------------------------- conv1 agg
// 8 lanes per node, online softmax + butterfly merge; fused relu + W2 proj.
// blockIdx.y selects direction.
__global__ void k_agg1(const __half* __restrict__ h1f, const float* __restrict__ s1sf, const float* __restrict__ s1df,
                       const int* __restrict__ offf, const int* __restrict__ csrf,
                       const __half* __restrict__ h1r, const float* __restrict__ s1sr, const float* __restrict__ s1dr,
                       const int* __restrict__ offr, const int* __restrict__ csrr,
                       const float* __restrict__ b1, const float* __restrict__ W2,
                       const float* __restrict__ as2, const float* __restrict__ ad2,
                       const float* __restrict__ b1r, const float* __restrict__ W2r,
                       const float* __restrict__ as2r, const float* __restrict__ ad2r,
                       float2* __restrict__ p2f, float* __restrict__ s2df,
                       float2* __restrict__ p2r, float* __restrict__ s2dr, int N) {
    int dir = blockIdx.y;
    const __half* h1 = dir ? h1r : h1f;
    const float* s1s = dir ? s1sr : s1sf;
    const float* s1d = dir ? s1dr : s1df;
    const int* off = dir ? offr : offf;
    const int* csr = dir ? csrr : csrf;
    const float* b1_ = dir ? b1r : b1;
    const float* W2_ = dir ? W2r : W2;
    float as2v = dir ? as2r[0] : as2[0];
    float ad2v = dir ? ad2r[0] : ad2[0];
    float2* p2 = dir ? p2r : p2f;
    float* s2d = dir ? s2dr : s2df;

    int tid = blockIdx.x * blockDim.x + threadIdx.x;
    int v = tid >> 3;
    int lane = tid & 7;
    if (v >= N) return;
    float sd = s1d[v];
    int st = off[v], en = off[v + 1];
    float m = NEG_SENT, d = 0.f;
    float acc[16];
#pragma unroll
    for (int k = 0; k < 16; k++) acc[k] = 0.f;
    if (lane == 0) {  // self loop
        m = lrelu(s1s[v] + sd);
        d = 1.f;
        const float4* hp = (const float4*)(h1 + 16 * v);
        union { float4 f4[2]; __half2 h2[8]; } hh;
        hh.f4[0] = hp[0]; hh.f4[1] = hp[1];
#pragma unroll
        for (int r = 0; r < 8; r++) {
            float2 f = __half22float2(hh.h2[r]);
            acc[2 * r] = f.x; acc[2 * r + 1] = f.y;
        }
    }
    for (int j = st + lane; j < en; j += 8) {
        int u = __builtin_nontemporal_load(csr + j);
        float e = lrelu(s1s[u] + sd);
        float mn = fmaxf(m, e);
        float scl = __expf(m - mn);
        float du = __expf(e - mn);
        d = d * scl + du;
        const float4* hp = (const float4*)(h1 + 16 * u);
        union { float4 f4[2]; __half2 h2[8]; } hh;
        hh.f4[0] = hp[0]; hh.f4[1] = hp[1];
#pragma unroll
        for (int r = 0; r < 8; r++) {
            float2 f = __half22float2(hh.h2[r]);
            acc[2 * r]     = acc[2 * r]     * scl + du * f.x;
            acc[2 * r + 1] = acc[2 * r + 1] * scl + du * f.y;
        }
        m = mn;
    }
    // merge 8 lane-partials (butterfly; all lanes end with full result)
#pragma unroll
    for (int mask = 1; mask < 8; mask <<= 1) {
        float mo = __shfl_xor(m, mask);
        float dd = __shfl_xor(d, mask);
        float mn = fmaxf(m, mo);
        float sa = __expf(m - mn);
        float sb = __expf(mo - mn);
        d = d * sa + dd * sb;
#pragma unroll
        for (int k = 0; k < 16; k++)
            acc[k] = acc[k] * sa + __shfl_xor(acc[k], mask) * sb;
        m = mn;
    }
    float inv = 1.f / (d + 1e-16f);
    float h2v = 0.f;
#pragma unroll
    for (int k = 0; k < 16; k++) {
        float o = fmaxf(acc[k] * inv + b1_[k], 0.f);
        h2v += o * W2_[k];
    }
    if (lane == 0) {
        p2[v] = make_float2(h2v, h2v * as2v);
        s2d[v] = h2v * ad2v;
    }
}

// ---------------------------------------------------------------- conv2 agg + combine
__global__ void k_agg2(const float2* __restrict__ p2f, const float* __restrict__ s2df,
                       const int* __restrict__ offf, const int* __restrict__ csrf,
                       const float2* __restrict__ p2r, const float* __restrict__ s2dr,
                       const int* __restrict__ offr, const int* __restrict__ csrr,
                       const float* __restrict__ b2, const float* __restrict__ b2r,
                       float* __restrict__ out, int N) {
    int tid = blockIdx.x * blockDim.x + threadIdx.x;
    int v = tid >> 3;
    int lane = tid & 7;
    if (v >= N) return;
    float res[2];
#pragma unroll
    for (int dir = 0; dir < 2; dir++) {
        const float2* p2 = dir ? p2r : p2f;
        const float* s2d = dir ? s2dr : s2df;
        const int* off = dir ? offr : offf;
        const int* csr = dir ? csrr : csrf;
        float bias = dir ? b2r[0] : b2[0];
        float sd = s2d[v];
        int st = off[v], en = off[v + 1];
        float m = NEG_SENT, d = 0.f, a = 0.f;
        if (lane == 0) {  // self loop
            float2 ts = p2[v];
            m = lrelu(ts.y + sd);
            d = 1.f;
            a = ts.x;
        }
        for (int j = st + lane; j < en; j += 8) {
            int u = __builtin_nontemporal_load(csr + j);
            float2 t = p2[u];
            float e = lrelu(t.y + sd);
            float mn = fmaxf(m, e);
            float scl = __expf(m - mn);
            float du = __expf(e - mn);
            d = d * scl + du;
            a = a * scl + du * t.x;
            m = mn;
        }
#pragma unroll
        for (int mask = 1; mask < 8; mask <<= 1) {
            float mo = __shfl_xor(m, mask);
            float dd = __shfl_xor(d, mask);
            float ao = __shfl_xor(a, mask);
            float mn = fmaxf(m, mo);
            float sa = __expf(m - mn);
            float sb = __expf(mo - mn);
            d = d * sa + dd * sb;
            a = a * sa + ao * sb;
            m = mn;
        }
        res[dir] = a / (d + 1e-16f) + bias;
    }
    if (lane == 0) out[v] = 0.5f * (res[0] + res[1]);
}

// ================================================================ launch
extern "C" void kernel_launch(void* const* d_in, const int* in_sizes, int n_in,
                              void* d_out, int out_size, void* d_ws, size_t ws_size,
                              hipStream_t stream) {
    const float* x   = (const float*)d_in[0];
    const void*  ei  = d_in[1];
    const float* W1  = (const float*)d_in[2];
    const float* as1 = (const float*)d_in[3];
    const float* ad1 = (const float*)d_in[4];
    const float* b1  = (const float*)d_in[5];
    const float* W2  = (const float*)d_in[6];
    const float* as2 = (const float*)d_in[7];
    const float* ad2 = (const float*)d_in[8];
    const float* b2  = (const float*)d_in[9];
    const float* W1r  = (const float*)d_in[10];
    const float* as1r = (const float*)d_in[11];
    const float* ad1r = (const float*)d_in[12];
    const float* b1r  = (const float*)d_in[13];
    const float* W2r  = (const float*)d_in[14];
    const float* as2r = (const float*)d_in[15];
    const float* ad2r = (const float*)d_in[16];
    const float* b2r  = (const float*)d_in[17];

    const int N = in_sizes[0] / 3;
    const long long E = in_sizes[1] / 2;
    const int NB = (N + BNODES - 1) >> BSH;

    char* w = (char*)d_ws;
    size_t o = 0;
    auto A = [&](size_t bytes) { o = (o + 255) & ~(size_t)255; size_t r = o; o += bytes; return r; };
    size_t oFlag = A(64);
    size_t oH1f  = A(sizeof(__half) * 16 * N);
    size_t oH1r  = A(sizeof(__half) * 16 * N);
    size_t oS1sf = A(sizeof(float) * N);
    size_t oS1df = A(sizeof(float) * N);
    size_t oS1sr = A(sizeof(float) * N);
    size_t oS1dr = A(sizeof(float) * N);
    size_t oP2f  = A(sizeof(float2) * N);
    size_t oS2df = A(sizeof(float) * N);
    size_t oP2r  = A(sizeof(float2) * N);
    size_t oS2dr = A(sizeof(float) * N);
    size_t oCnt  = A(sizeof(int) * 2 * (size_t)GPART * NB);
    size_t oBB   = A(sizeof(int) * 2 * (NB + 1));
    size_t oBinf = A(sizeof(unsigned) * E);
    size_t oBinr = A(sizeof(unsigned) * E);
    size_t oCsrf = A(sizeof(int) * E);
    size_t oCsrr = A(sizeof(int) * E);
    size_t oOfff = A(sizeof(int) * (N + 1));
    size_t oOffr = A(sizeof(int) * (N + 1));
    (void)ws_size; (void)n_in; (void)out_size;

    int*      flag = (int*)(w + oFlag);
    __half*   h1f  = (__half*)(w + oH1f);
    __half*   h1r  = (__half*)(w + oH1r);
    float*    s1sf = (float*)(w + oS1sf);
    float*    s1df = (float*)(w + oS1df);
    float*    s1sr = (float*)(w + oS1sr);
    float*    s1dr = (float*)(w + oS1dr);
    float2*   p2f  = (float2*)(w + oP2f);
    float*    s2df = (float*)(w + oS2df);
    float2*   p2r  = (float2*)(w + oP2r);
    float*    s2dr = (float*)(w + oS2dr);
    int* counts = (int*)(w + oCnt);
    int* bb     = (int*)(w + oBB);
    unsigned* binf = (unsigned*)(w + oBinf);
    unsigned* binr = (unsigned*)(w + oBinr);
    int* csrf = (int*)(w + oCsrf);
    int* csrr = (int*)(w + oCsrr);
    int* offf = (int*)(w + oOfff);
    int* offr = (int*)(w + oOffr);

    dim3 gN((N + 255) / 256);
    dim3 gAgg((N * 8 + 255) / 256, 2);
    dim3 gAgg2((N * 8 + 255) / 256);

    k_flag<<<1, 64, 0, stream>>>((const unsigned long long*)ei, flag);
    k_prep<<<gN, 256, 0, stream>>>(x, W1, as1, ad1, W1r, as1r, ad1r,
                                   h1f, h1r, s1sf, s1df, s1sr, s1dr, N);
    k_hist5<<<GPART, 512, 0, stream>>>(ei, E, flag, counts, NB);
    k_scan6<<<1, 1024, 0, stream>>>(counts, bb, NB);
    k_scatter7<<<GPART, 512, 0, stream>>>(ei, E, flag, counts, NB, binf, binr);
    k_fill8<<<2 * NB, 512, 0, stream>>>(binf, binr, bb, offf, offr, csrf, csrr, NB, N);
    k_agg1<<<gAgg, 256, 0, stream>>>(h1f, s1sf, s1df, offf, csrf,
                                     h1r, s1sr, s1dr, offr, csrr,
                                     b1, W2, as2, ad2, b1r, W2r, as2r, ad2r,
                                     p2f, s2df, p2r, s2dr, N);
    k_agg2<<<gAgg2, 256, 0, stream>>>(p2f, s2df, offf, csrf, p2r, s2dr, offr, csrr,
                                      b2, b2r, (float*)d_out, N);
}